// Round 1
// baseline (233.669 us; speedup 1.0000x reference)
//
#include <hip/hip_runtime.h>
#include <hip/hip_bf16.h>
#include <stdint.h>

// Cheb graph conv: out[b,o,m,t] = sum_{k,n,c} T_k[n,m] x[b,c,n,t] Theta[k,c,o]
// Folded:  W[(o,m)][(c,n)] = sum_k T_k[n,m] Theta[k,c,o]
//          out_b (768x512) = W @ x_b (768x512) per batch, bf16 MFMA.
// R6 (this round): latency-bound fix.
//  - A fragments loaded DIRECT from global (Wp is packed fragment-contiguous:
//    each wave load = contiguous 1KB, L2-hot). No As LDS, no A staging barrier.
//  - Bs double-buffered (2 x 8KB), ONE __syncthreads per kt (write buf ->
//    barrier -> read buf; dbuf makes the second barrier unnecessary).
//  - Bs rows 64B + XOR swizzle  off ^= (t&7)<<4  -> conflict-free b128 writes
//    AND reads (8 lanes per 16B-unit residue = b128 minimum).
//  - x prefetch 2-deep (XrA/XrB named sets, kt-loop unrolled x2 so all reg
//    indices are compile-time; rule #20), covers L3 latency (~600-900 cy).
//  - nontemporal out stores (out is write-once) to protect x/W L2 residency.

#define NV 24
#define CIN 32
#define COUT 32
#define TDIM 512
#define BATCH 64
#define MDIM 768   // COUT*NV
#define KD 768     // CIN*NV
#define BM 128
#define BN 128
#define BK 32
#define NKT (KD / BK)    // 24
#define NTT (TDIM / BN)  // 4
#define NMT (MDIM / BM)  // 6
#define BLOB (BM * BK)   // 4096 shorts = 8 KB per (mt,kt) A blob
#define BSH (BN * BK)    // 4096 shorts = 8 KB per Bs buffer (128 rows x 64B)

typedef __attribute__((ext_vector_type(8))) short short8v;  // 8 bf16
typedef __attribute__((ext_vector_type(4))) float float4v;  // 4 fp32 acc

union PackU { short8v s; __hip_bfloat162 h[4]; };

__device__ inline unsigned short f2bf(float f) {
    unsigned int u = __float_as_uint(f);
    unsigned int r = (u + 0x7fffu + ((u >> 16) & 1u)) >> 16;
    return (unsigned short)r;
}

// ---------------------------------------------------------------------------
// prep_w: 64 blocks x 256 thr; writes Wp packed [mt][kt][128 m][32 k] bf16.
// NV*NV=576 > 256 threads: per-element phases must be strided loops.
__global__ __launch_bounds__(256) void prep_w(const float* __restrict__ adj,
                                              const float* __restrict__ Theta,
                                              unsigned short* __restrict__ Wp) {
    __shared__ float adjS[NV * NV];
    __shared__ float disS[NV];
    __shared__ float LS[NV * NV];
    __shared__ float T2S[NV * NV];
    int tid = threadIdx.x;
    for (int e = tid; e < NV * NV; e += 256) adjS[e] = adj[e];
    __syncthreads();
    if (tid < NV) {
        float d = 0.f;
        for (int j = 0; j < NV; ++j) d += adjS[tid * NV + j];
        disS[tid] = (d > 0.f) ? rsqrtf(d) : 0.f;
    }
    __syncthreads();
    for (int e = tid; e < NV * NV; e += 256) {
        int i = e / NV, j = e % NV;
        LS[e] = disS[i] * adjS[j * NV + i] * disS[j];  // L = D^-1/2 A^T D^-1/2
    }
    __syncthreads();
    for (int e = tid; e < NV * NV; e += 256) {
        int i = e / NV, j = e % NV;
        float s = 0.f;
        for (int p = 0; p < NV; ++p) s += LS[i * NV + p] * LS[p * NV + j];
        T2S[e] = 2.f * s - (i == j ? 1.f : 0.f);
    }
    __syncthreads();
    int r0 = blockIdx.x * (MDIM / 64);  // 12 rows per block
    for (int e = tid; e < (MDIM / 64) * KD; e += 256) {
        int lr = e / KD, col = e % KD;
        int row = r0 + lr;
        int o = row / NV, m = row % NV;
        int c = col / NV, n = col % NV;
        float th0 = Theta[0 * CIN * COUT + c * COUT + o];
        float th1 = Theta[1 * CIN * COUT + c * COUT + o];
        float th2 = Theta[2 * CIN * COUT + c * COUT + o];
        float v = (n == m ? th0 : 0.f) + LS[n * NV + m] * th1 + T2S[n * NV + m] * th2;
        size_t idx = (((size_t)(row >> 7) * NKT + (col >> 5)) * BM + (row & 127)) * BK + (col & 31);
        Wp[idx] = f2bf(v);
    }
}

// ---------------------------------------------------------------------------
// One kt step. BUF is a literal 0/1; XC is the x-register set loaded for KT
// (prefetched 2 iters ago); AC holds A fragments for KT; AN receives KT+1.
#define STEP(KT, BUF, XC, AC, AN)                                              \
    do {                                                                       \
        PackU u0, u1;                                                          \
        _Pragma("unroll")                                                      \
        for (int i = 0; i < 4; ++i) {                                          \
            u0.h[i] = __float22bfloat162_rn({XC[2 * i], XC[2 * i + 1]});       \
            u1.h[i] = __float22bfloat162_rn({XC[8 + 2 * i], XC[8 + 2 * i + 1]}); \
        }                                                                      \
        *(short8v*)(Bs + (BUF) * BSH + wr0) = u0.s;                            \
        *(short8v*)(Bs + (BUF) * BSH + wr0 + 64 * BK) = u1.s;                  \
        if ((KT) + 1 < NKT) { /* A(kt+1) -> regs, 1-deep (L2-hot W) */         \
            const short8v* Ap_ = (const short8v*)(Ab + (size_t)((KT) + 1) * BLOB); \
            _Pragma("unroll")                                                  \
            for (int i = 0; i < 4; ++i) AN[i] = Ap_[afr + i * 64];             \
        }                                                                      \
        if ((KT) + 2 < NKT) { /* x(kt+2) -> same regs just consumed by pack */ \
            const float* xr_ = xb + (size_t)(((KT) + 2) * BK + kq * 8) * TDIM; \
            _Pragma("unroll")                                                  \
            for (int kk = 0; kk < 8; ++kk) {                                   \
                XC[kk] = xr_[(size_t)kk * TDIM + tp];                          \
                XC[8 + kk] = xr_[(size_t)kk * TDIM + tp + 64];                 \
            }                                                                  \
        }                                                                      \
        __syncthreads(); /* lgkm-only drain; global prefetches stay in flight */ \
        short8v bb[4];                                                         \
        _Pragma("unroll")                                                      \
        for (int j = 0; j < 4; ++j)                                            \
            bb[j] = *(const short8v*)(Bs + (BUF) * BSH + rb + j * (16 * BK));  \
        _Pragma("unroll")                                                      \
        for (int i = 0; i < 4; ++i)                                            \
            _Pragma("unroll")                                                  \
            for (int j = 0; j < 4; ++j)                                        \
                acc[i][j] = __builtin_amdgcn_mfma_f32_16x16x32_bf16(           \
                    AC[i], bb[j], acc[i][j], 0, 0, 0);                         \
    } while (0)

// gemm_fused: out tile (128m x 128t) = Wp tile @ x^T tile.
// grid 1536 (XCD-swizzled); 256 thr = 4 waves (2x2 of 64x64).
__global__ __launch_bounds__(256, 3) void gemm_fused(const unsigned short* __restrict__ Wp,
                                                     const float* __restrict__ x,
                                                     float* __restrict__ out) {
    // Bs[t][k] bf16, 64B rows, XOR-swizzled; double-buffered = 16 KB total.
    __shared__ __attribute__((aligned(16))) unsigned short Bs[2 * BSH];

    // XCD swizzle: the 6 mt-sharers of an x-slice land on one XCD window.
    int id = blockIdx.x;
    int hi = id / 48;
    int rem = id - hi * 48;
    int mt = rem >> 3;               // 0..5
    int g = hi * 8 + (rem & 7);      // 0..255
    int b = g >> 2;
    int tt = g & 3;

    int tid = threadIdx.x;
    int wave = tid >> 6;
    int lane = tid & 63;
    int quad = lane >> 4;
    int l16 = lane & 15;
    int wm = wave >> 1, wn = wave & 1;
    int kq = wave;      // x-stage: this wave covers k = kq*8 .. kq*8+7
    int tp = lane;      // x-stage: this thread covers t = tp and tp+64

    const unsigned short* Ab = Wp + (size_t)mt * NKT * BLOB;
    const float* xb = x + (size_t)b * KD * TDIM + tt * BN;

    // Swizzled Bs offsets (shorts). unit = 16B; off ^= (t&7)<<4 bytes.
    // Write: row tp (and tp+64: same t&7, +2048 shorts), k-units = kq.
    int wr0 = (tp * BK + kq * 8) ^ ((tp & 7) * 8);
    // Read: t = wn*64 + j*16 + l16 (t&7 == l16&7), k-unit = quad.
    int rb = ((wn * 64 + l16) * BK + quad * 8) ^ ((l16 & 7) * 8);
    // A fragment index in short8v units: m = wm*64 + i*16 + l16, k-unit = quad.
    int afr = (wm * 64 + l16) * 4 + quad;

    const float4v zero4 = {0.f, 0.f, 0.f, 0.f};
    float4v acc[4][4];
#pragma unroll
    for (int i = 0; i < 4; ++i)
#pragma unroll
        for (int j = 0; j < 4; ++j) acc[i][j] = zero4;

    float XrA[16], XrB[16];     // 2-deep x prefetch (even/odd kt)
    short8v Aev[4], Aod[4];     // 1-deep A fragment prefetch

    // prologue: x(0)->XrA, A(0)->Aev, x(1)->XrB
    {
        const float* xr = xb + (size_t)(kq * 8) * TDIM;
#pragma unroll
        for (int kk = 0; kk < 8; ++kk) {
            XrA[kk] = xr[(size_t)kk * TDIM + tp];
            XrA[8 + kk] = xr[(size_t)kk * TDIM + tp + 64];
        }
        const short8v* Ap = (const short8v*)Ab;
#pragma unroll
        for (int i = 0; i < 4; ++i) Aev[i] = Ap[afr + i * 64];
        const float* xr1 = xb + (size_t)(BK + kq * 8) * TDIM;
#pragma unroll
        for (int kk = 0; kk < 8; ++kk) {
            XrB[kk] = xr1[(size_t)kk * TDIM + tp];
            XrB[8 + kk] = xr1[(size_t)kk * TDIM + tp + 64];
        }
    }

    for (int kt = 0; kt < NKT; kt += 2) {
        STEP(kt, 0, XrA, Aev, Aod);
        STEP(kt + 1, 1, XrB, Aod, Aev);
    }

    // C/D layout (m89): col = lane&15, row = quad*4 + reg
    float* outB = out + (size_t)b * MDIM * TDIM;
    int rbase = mt * BM + wm * 64;
    int cbase = tt * BN + wn * 64;
#pragma unroll
    for (int i = 0; i < 4; ++i) {
#pragma unroll
        for (int j = 0; j < 4; ++j) {
            int row0 = rbase + i * 16 + quad * 4;
            int col = cbase + j * 16 + l16;
#pragma unroll
            for (int r = 0; r < 4; ++r)
                __builtin_nontemporal_store(acc[i][j][r],
                                            &outB[(size_t)(row0 + r) * TDIM + col]);
        }
    }
}

// ---------------------------------------------------------------------------
extern "C" void kernel_launch(void* const* d_in, const int* in_sizes, int n_in,
                              void* d_out, int out_size, void* d_ws, size_t ws_size,
                              hipStream_t stream) {
    const float* x = (const float*)d_in[0];      // (64,32,24,512) fp32
    const float* adj = (const float*)d_in[1];    // (24,24) fp32
    const float* Theta = (const float*)d_in[2];  // (3,32,32) fp32
    float* out = (float*)d_out;                  // (64,32,24,512) fp32

    // ws: Wp bf16 packed blobs only (1.125 MB)
    unsigned short* Wp = (unsigned short*)d_ws;

    prep_w<<<64, 256, 0, stream>>>(adj, Theta, Wp);
    gemm_fused<<<NMT * NTT * BATCH, 256, 0, stream>>>(Wp, x, out);
}